// Round 9
// baseline (96.320 us; speedup 1.0000x reference)
//
#include <hip/hip_runtime.h>

#define NPTS 16384
#define TH 33.33f

typedef __attribute__((ext_vector_type(8)))  __bf16 bf16x8;
typedef __attribute__((ext_vector_type(16))) float  f32x16;
typedef __attribute__((ext_vector_type(16))) unsigned u32x16;

__device__ __forceinline__ unsigned short f2bf(float x) {
    unsigned u = __float_as_uint(x);
    u += 0x7FFFu + ((u >> 16) & 1u);
    return (unsigned short)(u >> 16);
}
__device__ __forceinline__ float bf2f(unsigned short h) {
    return __uint_as_float(((unsigned)h) << 16);
}
__device__ __forceinline__ unsigned umin_(unsigned a, unsigned b) { return a < b ? a : b; }

union UV { uint4 v; bf16x8 h; unsigned short s[8]; };

// ws: pfmt byte[4 set][16384 pt][32] (4 MB) + d2part float[4 db][128 rb][8 seg][128] (2 MB).
// fragment map: elem = (g*32 + idx)*8 + j with k = g*8 + j (verified R2-R16)
// A k: [qh(3), ql(3), qh(2) | zh, 1,1,1, 1.0, 0,0,0]
// B k: [ph(3), ph(3), pl(2) | zl, -hp0,-hp1,-hp2, -32, 0,0,0]
// score s'' = q.p - hp - 32 (strictly negative) ; d^2 = 2*(hq - 32 - s'')
// Fold: negative floats => float-max == uint-min on bits; umin3 chains (R18).
//
// === DIAGNOSIS LEDGER ===
// R24 = BUG, not a result: loop bound 256 instead of 32 => each block read 512KB past
//   its 64KB seg slice (absmax 5.9e-2). Theory untested. R25 = R24 with i<32 ONLY.
// R23 (async DMA staging, 8 waves) = NEUTRAL at 40.5us, ALL counters clean => staging
//   pathologies were non-binding. Binding pair hypothesis: (a) 1-tile/wave halves LDS
//   reuse -> ds_read_b128 demand 20.5us/CU > matrix 13.7us/CU; (b) per-chunk barrier
//   re-convoys waves, killing phase drift.
// R25 main loop: NO LDS, NO BARRIERS. B loaded per-iter from pfmt (L2-resident 4MB;
//   seg slice 64KB; 4 waves/block share lines via L1) via 2x global_load_dwordx4 ->
//   2 MFMA -> 16 umin3. Waves free-run. 64-reg footprint unchanged.
// R22: hoisted staging regs @ 8 waves = spill (64-cap). ILP closed at both occupancy
//   tiers (R19: 128-cap, R22: 64-cap). R21: (256,8) occupancy step REAL; quantum is
//   power-of-2 (R20). R17: in-loop col-fold = +25us. R18: int fold neutral (kept).
// m119: MFMA 32x32x16 ~= 32 cyc/SIMD. Matrix floor 13.7us. m134: ds_read_b128 ~12cyc.
//
// === FROZEN LEDGER (R2-R16) ===
// R11: any ds_write must be lane-consecutive-16B. R5/R7: no inline asm on MFMA results.
// R15/R16: unroll-2 / shuffle-epilogue = +14us (reg tax). Keep unroll 1 + LDS-scratch
//   epilogue (per-wave private region, intra-wave lgkmcnt ordering, no barrier needed).
// TIMING: dur_us includes fixed ~48us harness re-poison fill (268 MB). Addressable
//   budget = prep (~0.5) + chamfer + merge (~1.3).

// ---- prep: convert all points of both tensors/batches to the 32B LDS-image format ----
// set: 0,1 = src[b] ; 2,3 = tgt[b].  point p -> offset (p>>5)*1024 + (p&31)*16 (+512 for c1)
__global__ __launch_bounds__(256) void prep_kernel(
        const float* __restrict__ src, const float* __restrict__ tgt,
        unsigned char* __restrict__ pfmt, float* __restrict__ out)
{
    const int set = blockIdx.y;                   // 4 sets
    const int chunk = blockIdx.x;                 // 64 chunks x 256 pts
    const int tid = threadIdx.x;
    if (set == 0 && chunk == 0 && tid < 2) out[tid] = 0.0f;   // replaces memset node
    const float* base = (set < 2 ? src : tgt) + (size_t)(set & 1) * NPTS * 3;
    const int p = chunk * 256 + tid;
    const float x = base[p * 3 + 0], y = base[p * 3 + 1], z = base[p * 3 + 2];

    float hp = 0.5f * fmaf(z, z, fmaf(y, y, x * x));
    unsigned short xh = f2bf(x), yh = f2bf(y), zh = f2bf(z);
    unsigned short xl = f2bf(x - bf2f(xh)), yl = f2bf(y - bf2f(yh)), zl = f2bf(z - bf2f(zh));
    float rr = hp;
    unsigned short h0 = f2bf(rr); rr -= bf2f(h0);
    unsigned short h1 = f2bf(rr); rr -= bf2f(h1);
    unsigned short h2 = f2bf(rr);
    UV c0, c1;
    c0.s[0]=xh; c0.s[1]=yh; c0.s[2]=zh; c0.s[3]=xh; c0.s[4]=yh; c0.s[5]=zh; c0.s[6]=xl; c0.s[7]=yl;
    c1.s[0]=zl; c1.s[1]=(unsigned short)(h0^0x8000); c1.s[2]=(unsigned short)(h1^0x8000);
    c1.s[3]=(unsigned short)(h2^0x8000);
    c1.s[4]=0xC200;                     // bf16(-32) bias, pairs with A k12 = 1.0
    c1.s[5]=0; c1.s[6]=0; c1.s[7]=0;

    unsigned char* ob = pfmt + (size_t)set * NPTS * 32
                             + (size_t)(p >> 5) * 1024 + (size_t)(p & 31) * 16;
    *(uint4*)(ob)       = c0.v;
    *(uint4*)(ob + 512) = c1.v;
}

__global__ __launch_bounds__(256, 8) void chamfer_kernel(
        const float* __restrict__ src, const float* __restrict__ tgt,
        const unsigned char* __restrict__ pfmt, float* __restrict__ d2part)
{
    const int db = blockIdx.y, dir = db >> 1, b = db & 1;
    const int rowblock = blockIdx.x >> 3, seg = blockIdx.x & 7;   // 128 rowblocks x 8 segs
    const int tid = threadIdx.x, wave = tid >> 6, lane = tid & 63;
    const int g = lane >> 5, cc = lane & 31;
    const float* qp = (dir == 0 ? src : tgt) + (size_t)b * NPTS * 3;
    const int pset = (dir == 0 ? 2 + b : b);
    const unsigned char* ps = pfmt + (size_t)pset * NPTS * 32 + (size_t)seg * 2048 * 32;
    const unsigned short one = 0x3F80;

    // LDS only for the epilogue scratch (per-wave private; no barriers anywhere)
    __shared__ alignas(16) unsigned char smem[16896];
    unsigned* scratch = (unsigned*)smem;

    // ---- A fragment + hq: ONE 32-row tile per wave (acc 16 regs) ----
    const int rt = rowblock * 4 + wave;
    bf16x8 afrag; float hq;
    {
        int r = rt * 32 + cc;
        float x = qp[r * 3 + 0], y = qp[r * 3 + 1], z = qp[r * 3 + 2];
        hq = 0.5f * fmaf(z, z, fmaf(y, y, x * x));
        unsigned short xh = f2bf(x), yh = f2bf(y), zh = f2bf(z);
        unsigned short xl = f2bf(x - bf2f(xh)), yl = f2bf(y - bf2f(yh)), zl = f2bf(z - bf2f(zh));
        UV f0, f1, rv;
        f0.s[0]=xh; f0.s[1]=yh; f0.s[2]=zh; f0.s[3]=xl; f0.s[4]=yl; f0.s[5]=zl; f0.s[6]=xh; f0.s[7]=yh;
        f1.s[0]=zh; f1.s[1]=one; f1.s[2]=one; f1.s[3]=one;
        f1.s[4]=one;                    // k12: pairs with B's bf16(-32) bias slot
        f1.s[5]=0; f1.s[6]=0; f1.s[7]=0;
        rv.v = g ? f1.v : f0.v;
        afrag = rv.h;
    }

    u32x16 m0 = 0xFF800000u;            // bits of -inf: umin identity here
    const f32x16 zc = 0.0f;

    // R25 main loop: direct L2->VGPR->MFMA over the 64KB seg slice = 32 iters x 2048B.
    // Per iter: 2 coalesced dwordx4 loads/lane, 2 MFMA, 16 umin3. No LDS, no barriers.
    const unsigned char* gq = ps + (size_t)lane * 16;
#pragma unroll 1
    for (int i = 0; i < 32; ++i) {                // 2048 pts / 64 per iter  (R24 bug: was 256)
        UV u0, u1;
        u0.v = *(const uint4*)(gq + (size_t)i * 2048);
        u1.v = *(const uint4*)(gq + (size_t)i * 2048 + 1024);
        f32x16 t0 = __builtin_amdgcn_mfma_f32_32x32x16_bf16(afrag, u0.h, zc, 0, 0, 0);
        f32x16 t1 = __builtin_amdgcn_mfma_f32_32x32x16_bf16(afrag, u1.h, zc, 0, 0, 0);
#pragma unroll
        for (int j = 0; j < 16; j++)
            m0[j] = umin_(umin_(__float_as_uint(t0[j]), __float_as_uint(t1[j])), m0[j]);
    }

    // ---- epilogue: acc bits -> padded LDS (per-wave private region) -> row reduce ----
    float* dst = d2part + (((size_t)(db * 128 + rowblock)) * 8 + seg) * 128;
    {
        unsigned* sc = scratch + wave * 1056;
#pragma unroll
        for (int j = 0; j < 16; j++) {
            int r0 = (j & 3) + 8 * (j >> 2) + 4 * g;
            sc[r0 * 33 + cc] = m0[j];
        }
        const unsigned* sr = sc + cc * 33 + g * 16;   // intra-wave dep: lgkmcnt orders it
        unsigned mx = 0xFF800000u;
#pragma unroll
        for (int k = 0; k < 16; k++) mx = umin_(mx, sr[k]);
        mx = umin_(mx, (unsigned)__shfl_xor((int)mx, 32, 64));
        if (lane < 32) {
            float sbi = __uint_as_float(mx);
            float d2 = 2.0f * (hq - 32.0f - sbi);
            float d = fminf(sqrtf(fmaxf(d2, 0.0f)), TH);
            dst[wave * 32 + lane] = d;
        }
    }
}

__global__ __launch_bounds__(256) void merge_kernel(const float* __restrict__ d2part,
                                                    float* __restrict__ out) {
    const int b = blockIdx.y;                     // batch
    const int slice = blockIdx.x;                 // 16 slices of 1024 rows
    const int tid = threadIdx.x;
    float s = 0.0f;
#pragma unroll
    for (int pass = 0; pass < 2; pass++) {        // dir 0 and dir 1
        const float* base = d2part + (size_t)(pass * 2 + b) * 128 * 8 * 128;
#pragma unroll
        for (int i = 0; i < 4; i++) {
            int r = slice * 1024 + i * 256 + tid;
            const float* p = base + (size_t)(r >> 7) * 1024 + (r & 127);
            float m = p[0];
#pragma unroll
            for (int sgi = 1; sgi < 8; sgi++) m = fminf(m, p[sgi * 128]);
            s += m;
        }
    }
#pragma unroll
    for (int off = 32; off > 0; off >>= 1) s += __shfl_down(s, off, 64);
    __shared__ float w[4];
    if ((tid & 63) == 0) w[tid >> 6] = s;
    __syncthreads();
    if (tid == 0) {
        float t = (w[0] + w[1]) + (w[2] + w[3]);
        atomicAdd(&out[b], t * (1.0f / (2.0f * NPTS)));  // (mean_fwd + mean_bwd) / 2
    }
}

extern "C" void kernel_launch(void* const* d_in, const int* in_sizes, int n_in,
                              void* d_out, int out_size, void* d_ws, size_t ws_size,
                              hipStream_t stream) {
    const float* src = (const float*)d_in[0];
    const float* tgt = (const float*)d_in[1];
    float* out = (float*)d_out;
    unsigned char* pfmt = (unsigned char*)d_ws;               // 4 MB
    float* d2part = (float*)(pfmt + (size_t)4 * 1024 * 1024); // 2 MB

    prep_kernel<<<dim3(64, 4), 256, 0, stream>>>(src, tgt, pfmt, out);
    chamfer_kernel<<<dim3(1024, 4), 256, 0, stream>>>(src, tgt, pfmt, d2part);
    merge_kernel<<<dim3(16, 2), 256, 0, stream>>>(d2part, out);
}

// Round 10
// 91.266 us; speedup vs baseline: 1.0554x; 1.0554x over previous
//
#include <hip/hip_runtime.h>

#define NPTS 16384
#define TH 33.33f

typedef __attribute__((ext_vector_type(8)))  __bf16 bf16x8;
typedef __attribute__((ext_vector_type(16))) float  f32x16;
typedef __attribute__((ext_vector_type(16))) unsigned u32x16;

__device__ __forceinline__ unsigned short f2bf(float x) {
    unsigned u = __float_as_uint(x);
    u += 0x7FFFu + ((u >> 16) & 1u);
    return (unsigned short)(u >> 16);
}
__device__ __forceinline__ float bf2f(unsigned short h) {
    return __uint_as_float(((unsigned)h) << 16);
}
__device__ __forceinline__ unsigned umin_(unsigned a, unsigned b) { return a < b ? a : b; }

union UV { uint4 v; bf16x8 h; unsigned short s[8]; };

// ws: pfmt byte[4 set][16384 pt][32] (4 MB) + d2part float[4 db][32 rb][8 seg][512] (2 MB).
// fragment map: elem = (g*32 + idx)*8 + j with k = g*8 + j (verified R2-R16)
// A k: [qh(3), ql(3), qh(2) | zh, 1,1,1, 1.0, 0,0,0]
// B k: [ph(3), ph(3), pl(2) | zl, -hp0,-hp1,-hp2, -32, 0,0,0]
// score s'' = q.p - hp - 32 (strictly negative) ; d^2 = 2*(hq - 32 - s'')
// Fold: negative floats => float-max == uint-min on bits; umin3 chains (R18).
//
// === DIAGNOSIS LEDGER ===
// THE INVARIANT (R2-R25): wall 40.5-49us across 6 structures, MfmaUtil 27-33%, at 4 AND
//   8 waves/SIMD, with/without barriers/LDS. Wall == SUM of per-wave serial chains
//   (~200cyc/iter x 32 iters x 16 block-waves/SIMD ~= 43us). Wave overlap ~nil because
//   chains are only ~30% matrix-dense. Fix: densify the CHAIN, not the wave count.
// R26 (this): 4 row-tiles/wave at (256,2) = 256 regs/wave tier (NEVER tried; R10's
//   4-tile spilled at the 128 tier). 8 MFMA per 2 loads: chain ~75% matrix-dense.
//   acc 64 + afrag 16 + t 32 + q-dbuf 32 + addr ~12 ~= 160 <= 256. Direct global
//   loads (no LDS/barriers in loop): 268MB L2 traffic same as staged aggregate.
// R25 (no-LDS @ 1-tile) = 48.8: 4x L2 traffic buys nothing at 2 MFMA/load. R24 = BUG.
// R23 (async DMA staged) = 40.5 clean counters. R21/R22: 8-wave tier real but neutral;
//   reg-prefetch spills at 64-cap. R19: spills at 128-cap. R20: occupancy quantum is
//   power-of-2. R17: in-loop col-fold = +25us. R18: int fold neutral (kept).
// m119: MFMA 32x32x16 ~= 32 cyc/SIMD; matrix floor 13.7us. m134: ds_read_b128 ~12cyc.
//
// === FROZEN LEDGER (R2-R16) ===
// R11: any ds_write lane-consecutive-16B. R5/R7: no inline asm on MFMA results.
// Epilogue: per-wave LDS scratch, intra-wave lgkmcnt ordering, no barrier (R23-verified).
// TIMING: dur_us includes fixed ~48us harness re-poison fill (268 MB). Addressable
//   budget = prep (~0.5) + chamfer + merge (~1.3).

// ---- prep: convert all points of both tensors/batches to the 32B MFMA-image format ----
// set: 0,1 = src[b] ; 2,3 = tgt[b].  point p -> offset (p>>5)*1024 + (p&31)*16 (+512 for c1)
__global__ __launch_bounds__(256) void prep_kernel(
        const float* __restrict__ src, const float* __restrict__ tgt,
        unsigned char* __restrict__ pfmt, float* __restrict__ out)
{
    const int set = blockIdx.y;                   // 4 sets
    const int chunk = blockIdx.x;                 // 64 chunks x 256 pts
    const int tid = threadIdx.x;
    if (set == 0 && chunk == 0 && tid < 2) out[tid] = 0.0f;   // replaces memset node
    const float* base = (set < 2 ? src : tgt) + (size_t)(set & 1) * NPTS * 3;
    const int p = chunk * 256 + tid;
    const float x = base[p * 3 + 0], y = base[p * 3 + 1], z = base[p * 3 + 2];

    float hp = 0.5f * fmaf(z, z, fmaf(y, y, x * x));
    unsigned short xh = f2bf(x), yh = f2bf(y), zh = f2bf(z);
    unsigned short xl = f2bf(x - bf2f(xh)), yl = f2bf(y - bf2f(yh)), zl = f2bf(z - bf2f(zh));
    float rr = hp;
    unsigned short h0 = f2bf(rr); rr -= bf2f(h0);
    unsigned short h1 = f2bf(rr); rr -= bf2f(h1);
    unsigned short h2 = f2bf(rr);
    UV c0, c1;
    c0.s[0]=xh; c0.s[1]=yh; c0.s[2]=zh; c0.s[3]=xh; c0.s[4]=yh; c0.s[5]=zh; c0.s[6]=xl; c0.s[7]=yl;
    c1.s[0]=zl; c1.s[1]=(unsigned short)(h0^0x8000); c1.s[2]=(unsigned short)(h1^0x8000);
    c1.s[3]=(unsigned short)(h2^0x8000);
    c1.s[4]=0xC200;                     // bf16(-32) bias, pairs with A k12 = 1.0
    c1.s[5]=0; c1.s[6]=0; c1.s[7]=0;

    unsigned char* ob = pfmt + (size_t)set * NPTS * 32
                             + (size_t)(p >> 5) * 1024 + (size_t)(p & 31) * 16;
    *(uint4*)(ob)       = c0.v;
    *(uint4*)(ob + 512) = c1.v;
}

// 8 MFMAs + 4 folds for one q-pair against 4 row-tile fragments
#define BODY(Q0, Q1) { \
    f32x16 t0, t1; \
    t0 = __builtin_amdgcn_mfma_f32_32x32x16_bf16(af0, Q0, zc, 0, 0, 0); \
    t1 = __builtin_amdgcn_mfma_f32_32x32x16_bf16(af0, Q1, zc, 0, 0, 0); \
    _Pragma("unroll") for (int j = 0; j < 16; j++) \
        mm0[j] = umin_(umin_(__float_as_uint(t0[j]), __float_as_uint(t1[j])), mm0[j]); \
    t0 = __builtin_amdgcn_mfma_f32_32x32x16_bf16(af1, Q0, zc, 0, 0, 0); \
    t1 = __builtin_amdgcn_mfma_f32_32x32x16_bf16(af1, Q1, zc, 0, 0, 0); \
    _Pragma("unroll") for (int j = 0; j < 16; j++) \
        mm1[j] = umin_(umin_(__float_as_uint(t0[j]), __float_as_uint(t1[j])), mm1[j]); \
    t0 = __builtin_amdgcn_mfma_f32_32x32x16_bf16(af2, Q0, zc, 0, 0, 0); \
    t1 = __builtin_amdgcn_mfma_f32_32x32x16_bf16(af2, Q1, zc, 0, 0, 0); \
    _Pragma("unroll") for (int j = 0; j < 16; j++) \
        mm2[j] = umin_(umin_(__float_as_uint(t0[j]), __float_as_uint(t1[j])), mm2[j]); \
    t0 = __builtin_amdgcn_mfma_f32_32x32x16_bf16(af3, Q0, zc, 0, 0, 0); \
    t1 = __builtin_amdgcn_mfma_f32_32x32x16_bf16(af3, Q1, zc, 0, 0, 0); \
    _Pragma("unroll") for (int j = 0; j < 16; j++) \
        mm3[j] = umin_(umin_(__float_as_uint(t0[j]), __float_as_uint(t1[j])), mm3[j]); }

// per-wave LDS-scratch row-reduce epilogue (R12 form; no barrier: intra-wave ordering)
#define EPILOG(MM, P) { \
    unsigned* sc = scratch + wave * 1056; \
    _Pragma("unroll") for (int j = 0; j < 16; j++) { \
        int r0 = (j & 3) + 8 * (j >> 2) + 4 * g; sc[r0 * 33 + cc] = MM[j]; } \
    const unsigned* sr = sc + cc * 33 + g * 16; \
    unsigned mx = 0xFF800000u; \
    _Pragma("unroll") for (int k = 0; k < 16; k++) mx = umin_(mx, sr[k]); \
    mx = umin_(mx, (unsigned)__shfl_xor((int)mx, 32, 64)); \
    if (lane < 32) { \
        float sbi = __uint_as_float(mx); \
        float d2 = 2.0f * (hq[P] - 32.0f - sbi); \
        float d = fminf(sqrtf(fmaxf(d2, 0.0f)), TH); \
        dst[wave * 128 + (P) * 32 + lane] = d; } }

__global__ __launch_bounds__(256, 2) void chamfer_kernel(
        const float* __restrict__ src, const float* __restrict__ tgt,
        const unsigned char* __restrict__ pfmt, float* __restrict__ d2part)
{
    const int db = blockIdx.y, dir = db >> 1, b = db & 1;
    const int rowblock = blockIdx.x >> 3, seg = blockIdx.x & 7;   // 32 rowblocks x 8 segs
    const int tid = threadIdx.x, wave = tid >> 6, lane = tid & 63;
    const int g = lane >> 5, cc = lane & 31;
    const float* qp = (dir == 0 ? src : tgt) + (size_t)b * NPTS * 3;
    const int pset = (dir == 0 ? 2 + b : b);
    const unsigned char* ps = pfmt + (size_t)pset * NPTS * 32 + (size_t)seg * 2048 * 32;
    const unsigned short one = 0x3F80;

    // LDS only for the epilogue scratch (per-wave private; no barriers anywhere)
    __shared__ alignas(16) unsigned char smem[16896];
    unsigned* scratch = (unsigned*)smem;

    // ---- A fragments + hq: FOUR 32-row tiles per wave (256-reg tier) ----
    bf16x8 af0, af1, af2, af3; float hq[4];
#pragma unroll
    for (int i = 0; i < 4; i++) {
        int r = (rowblock * 16 + wave * 4 + i) * 32 + cc;
        float x = qp[r * 3 + 0], y = qp[r * 3 + 1], z = qp[r * 3 + 2];
        hq[i] = 0.5f * fmaf(z, z, fmaf(y, y, x * x));
        unsigned short xh = f2bf(x), yh = f2bf(y), zh = f2bf(z);
        unsigned short xl = f2bf(x - bf2f(xh)), yl = f2bf(y - bf2f(yh)), zl = f2bf(z - bf2f(zh));
        UV f0, f1, rv;
        f0.s[0]=xh; f0.s[1]=yh; f0.s[2]=zh; f0.s[3]=xl; f0.s[4]=yl; f0.s[5]=zl; f0.s[6]=xh; f0.s[7]=yh;
        f1.s[0]=zh; f1.s[1]=one; f1.s[2]=one; f1.s[3]=one;
        f1.s[4]=one;                    // k12: pairs with B's bf16(-32) bias slot
        f1.s[5]=0; f1.s[6]=0; f1.s[7]=0;
        rv.v = g ? f1.v : f0.v;
        if (i == 0) af0 = rv.h; else if (i == 1) af1 = rv.h;
        else if (i == 2) af2 = rv.h; else af3 = rv.h;
    }

    u32x16 mm0 = 0xFF800000u, mm1 = 0xFF800000u, mm2 = 0xFF800000u, mm3 = 0xFF800000u;
    const f32x16 zc = 0.0f;

    // R26 main loop: 32 iters over the 64KB seg slice; 2 coalesced dwordx4 loads feed
    // 8 MFMAs (4 row-tiles x 2 col-tiles). a/b named-reg double buffer, 1-deep prefetch.
    const unsigned char* gq = ps + (size_t)lane * 16;
    UV a0, a1, b0, b1;
    a0.v = *(const uint4*)(gq);
    a1.v = *(const uint4*)(gq + 1024);
#pragma unroll 1
    for (int i = 0; i < 32; i += 2) {
        b0.v = *(const uint4*)(gq + (size_t)(i + 1) * 2048);
        b1.v = *(const uint4*)(gq + (size_t)(i + 1) * 2048 + 1024);
        BODY(a0.h, a1.h)
        if (i + 2 < 32) {
            a0.v = *(const uint4*)(gq + (size_t)(i + 2) * 2048);
            a1.v = *(const uint4*)(gq + (size_t)(i + 2) * 2048 + 1024);
        }
        BODY(b0.h, b1.h)
    }

    // ---- epilogue: 4 row-tiles, per-wave scratch reused sequentially ----
    float* dst = d2part + (((size_t)(db * 32 + rowblock)) * 8 + seg) * 512;
    EPILOG(mm0, 0)
    EPILOG(mm1, 1)
    EPILOG(mm2, 2)
    EPILOG(mm3, 3)
}

__global__ __launch_bounds__(256) void merge_kernel(const float* __restrict__ d2part,
                                                    float* __restrict__ out) {
    const int b = blockIdx.y;                     // batch
    const int slice = blockIdx.x;                 // 16 slices of 1024 rows
    const int tid = threadIdx.x;
    float s = 0.0f;
#pragma unroll
    for (int pass = 0; pass < 2; pass++) {        // dir 0 and dir 1
        const float* base = d2part + (size_t)(pass * 2 + b) * 32 * 8 * 512;
#pragma unroll
        for (int i = 0; i < 4; i++) {
            int r = slice * 1024 + i * 256 + tid;
            const float* p = base + (size_t)(r >> 9) * 4096 + (r & 511);
            float m = p[0];
#pragma unroll
            for (int sgi = 1; sgi < 8; sgi++) m = fminf(m, p[sgi * 512]);
            s += m;
        }
    }
#pragma unroll
    for (int off = 32; off > 0; off >>= 1) s += __shfl_down(s, off, 64);
    __shared__ float w[4];
    if ((tid & 63) == 0) w[tid >> 6] = s;
    __syncthreads();
    if (tid == 0) {
        float t = (w[0] + w[1]) + (w[2] + w[3]);
        atomicAdd(&out[b], t * (1.0f / (2.0f * NPTS)));  // (mean_fwd + mean_bwd) / 2
    }
}

extern "C" void kernel_launch(void* const* d_in, const int* in_sizes, int n_in,
                              void* d_out, int out_size, void* d_ws, size_t ws_size,
                              hipStream_t stream) {
    const float* src = (const float*)d_in[0];
    const float* tgt = (const float*)d_in[1];
    float* out = (float*)d_out;
    unsigned char* pfmt = (unsigned char*)d_ws;               // 4 MB
    float* d2part = (float*)(pfmt + (size_t)4 * 1024 * 1024); // 2 MB

    prep_kernel<<<dim3(64, 4), 256, 0, stream>>>(src, tgt, pfmt, out);
    chamfer_kernel<<<dim3(256, 4), 256, 0, stream>>>(src, tgt, pfmt, d2part);
    merge_kernel<<<dim3(16, 2), 256, 0, stream>>>(d2part, out);
}